// Round 1
// baseline (116.630 us; speedup 1.0000x reference)
//
#include <hip/hip_runtime.h>
#include <cfloat>
#include <cstdint>

#define TM 64
#define TN 64
#define KC 32
#define DSPLIT 4

// ---------------- generic small fp32 tiled GEMM: C[M,N] = A[M,K] @ B (+bias) ----
// BT=0: B is [K,N] row-major.  BT=1: B is [N,K] row-major (C = A @ B^T).
__global__ __launch_bounds__(256) void gemm_tile(
    const float* __restrict__ A, const float* __restrict__ B,
    const float* __restrict__ bias, float* __restrict__ Cm,
    int M, int N, int K, int BT)
{
    __shared__ float As[TM][KC + 1];
    __shared__ float Bs[KC][TN + 1];
    int t  = threadIdx.x;
    int m0 = blockIdx.y * TM, n0 = blockIdx.x * TN;
    int tr = (t >> 4) << 2;   // 0..60 step 4
    int tc = (t & 15) << 2;   // 0..60 step 4
    float acc[4][4] = {{0.f}};
    for (int k0 = 0; k0 < K; k0 += KC) {
        #pragma unroll
        for (int i = 0; i < 8; i++) {                 // A tile 64x32
            int lin = t + i * 256;
            int r = lin >> 5, c = lin & 31;
            As[r][c] = A[(size_t)(m0 + r) * K + (k0 + c)];
        }
        if (!BT) {
            #pragma unroll
            for (int i = 0; i < 8; i++) {             // B tile 32x64
                int lin = t + i * 256;
                int r = lin >> 6, c = lin & 63;
                Bs[r][c] = B[(size_t)(k0 + r) * N + (n0 + c)];
            }
        } else {
            #pragma unroll
            for (int i = 0; i < 8; i++) {             // B^T tile: rows are n
                int lin = t + i * 256;
                int n = lin >> 5, kk = lin & 31;
                Bs[kk][n] = B[(size_t)(n0 + n) * K + (k0 + kk)];  // pad 65 -> conflict-free
            }
        }
        __syncthreads();
        #pragma unroll
        for (int kk = 0; kk < KC; kk++) {
            float a0[4], b0[4];
            #pragma unroll
            for (int i = 0; i < 4; i++) a0[i] = As[tr + i][kk];
            #pragma unroll
            for (int j = 0; j < 4; j++) b0[j] = Bs[kk][tc + j];
            #pragma unroll
            for (int i = 0; i < 4; i++)
                #pragma unroll
                for (int j = 0; j < 4; j++) acc[i][j] += a0[i] * b0[j];
        }
        __syncthreads();
    }
    #pragma unroll
    for (int i = 0; i < 4; i++)
        #pragma unroll
        for (int j = 0; j < 4; j++) {
            float v = acc[i][j];
            if (bias) v += bias[n0 + tc + j];
            Cm[(size_t)(m0 + tr + i) * N + (n0 + tc + j)] = v;
        }
}

// ------------- s_part[b,g,ds] = sum_{d in chunk ds} feat[b,d,g] * z[b,d] -------
__global__ __launch_bounds__(256) void feat_dot(
    const float* __restrict__ feat, const float* __restrict__ z,
    float* __restrict__ s_part, int G, int D)
{
    int b = blockIdx.y, ds = blockIdx.x;
    int dchunk = D / DSPLIT;                       // 256
    __shared__ float zs[256];
    int t = threadIdx.x;
    if (t < dchunk) zs[t] = z[(size_t)b * D + (size_t)ds * dchunk + t];
    __syncthreads();
    if (t < G) {
        const float* fp = feat + ((size_t)b * D + (size_t)ds * dchunk) * G + t;
        float acc = 0.f;
        #pragma unroll 8
        for (int d = 0; d < dchunk; d++) acc += fp[(size_t)d * G] * zs[d];
        s_part[((size_t)b * G + t) * DSPLIT + ds] = acc;
    }
}

// ---------------------------- per-batch finalize -------------------------------
__global__ __launch_bounds__(256) void finalize(
    const float* __restrict__ boxes, const float* __restrict__ masks,
    const float* __restrict__ s_part, const float* __restrict__ y_new,
    const float* __restrict__ b_vs, const int* __restrict__ kptr,
    float* __restrict__ out_box, float* __restrict__ out_mask,
    float* __restrict__ out_max,
    int G, int AN, int CH, int CM, int H)
{
    __shared__ float ms[176];
    __shared__ int   selg[176];
    __shared__ float simv[176];
    __shared__ float redw[4];
    __shared__ float bb_s;
    __shared__ int   sel_pair[2];

    int b = blockIdx.x, t = threadIdx.x;
    int k = *kptr; if (k > G) k = G;

    // mean objectness over anchors
    if (t < G) {
        const float* bp = boxes + (size_t)(b * G + t) * AN * CH;
        float s = 0.f;
        for (int a = 0; a < AN; a++) s += bp[a * CH + 4];
        ms[t] = s / (float)AN;
    }
    // bb = dot(b_vs, y_new[b])
    float part = 0.f;
    for (int h = t; h < H; h += 256) part += b_vs[h] * y_new[(size_t)b * H + h];
    #pragma unroll
    for (int off = 32; off > 0; off >>= 1) part += __shfl_down(part, off);
    if ((t & 63) == 0) redw[t >> 6] = part;
    __syncthreads();
    if (t == 0) bb_s = redw[0] + redw[1] + redw[2] + redw[3];

    // exact top-k via rank (value desc, index asc) -- matches lax.top_k ties
    if (t < G) {
        float mv = ms[t];
        int rank = 0;
        for (int g = 0; g < G; g++) {
            float o = ms[g];
            rank += (int)((o > mv) | ((o == mv) & (g < t)));
        }
        if (rank < k) selg[rank] = t;
    }
    __syncthreads();

    if (t < k) {
        const float* sp = s_part + ((size_t)b * G + selg[t]) * DSPLIT;
        simv[t] = sp[0] + sp[1] + sp[2] + sp[3];
    }
    __syncthreads();

    if (t == 0) {
        float best = -FLT_MAX; int br = 0;
        for (int r = 0; r < k; r++) if (simv[r] > best) { best = simv[r]; br = r; }
        int gs = selg[br];
        const float* bp = boxes + (size_t)(b * G + gs) * AN * CH;
        float bo = -FLT_MAX; int ai = 0;
        for (int a = 0; a < AN; a++) { float o = bp[a * CH + 4]; if (o > bo) { bo = o; ai = a; } }
        float cx = bp[ai * CH + 0], cy = bp[ai * CH + 1];
        float w  = bp[ai * CH + 2], hh = bp[ai * CH + 3];
        float x1 = cx - w * 0.5f, y1 = cy - hh * 0.5f;
        out_box[(size_t)b * CH + 0] = x1;
        out_box[(size_t)b * CH + 1] = y1;
        out_box[(size_t)b * CH + 2] = x1 + w;
        out_box[(size_t)b * CH + 3] = y1 + hh;
        for (int c = 4; c < CH; c++) out_box[(size_t)b * CH + c] = bp[ai * CH + c];
        out_max[b] = best + bb_s;
        sel_pair[0] = gs; sel_pair[1] = ai;
    }
    __syncthreads();
    if (t < CM) {
        out_mask[(size_t)b * CM + t] =
            masks[((size_t)(b * G + sel_pair[0]) * AN + sel_pair[1]) * CM + t];
    }
}

extern "C" void kernel_launch(void* const* d_in, const int* in_sizes, int n_in,
                              void* d_out, int out_size, void* d_ws, size_t ws_size,
                              hipStream_t stream)
{
    const float* boxes = (const float*)d_in[0];
    const float* masks = (const float*)d_in[1];
    const float* feat  = (const float*)d_in[2];
    const float* lang  = (const float*)d_in[3];
    const float* W_vs  = (const float*)d_in[4];
    const float* b_vs  = (const float*)d_in[5];
    const float* W_ts  = (const float*)d_in[6];
    const float* b_ts  = (const float*)d_in[7];
    const int*   kptr  = (const int*)d_in[8];

    int H  = in_sizes[5];                 // 512
    int D  = in_sizes[4] / H;             // 1024
    int bs = in_sizes[3] / H;             // 256
    int G  = in_sizes[2] / (bs * D);      // 169
    int AN = 3;
    int CH = in_sizes[0] / (bs * G * AN); // 5
    int CM = in_sizes[1] / (bs * G * AN); // 32

    float* y_new  = (float*)d_ws;                    // bs*H
    float* z      = y_new + (size_t)bs * H;          // bs*D
    float* s_part = z + (size_t)bs * D;              // bs*G*DSPLIT

    float* out_box  = (float*)d_out;
    float* out_mask = out_box + (size_t)bs * CH;
    float* out_max  = out_mask + (size_t)bs * CM;

    // y_new[bs,H] = lang[bs,H] @ W_ts[H,H] + b_ts
    dim3 gA(H / TN, bs / TM);
    gemm_tile<<<gA, 256, 0, stream>>>(lang, W_ts, b_ts, y_new, bs, H, H, 0);
    // z[bs,D] = y_new[bs,H] @ W_vs[D,H]^T
    dim3 gB(D / TN, bs / TM);
    gemm_tile<<<gB, 256, 0, stream>>>(y_new, W_vs, nullptr, z, bs, D, H, 1);
    // s_part = partial feat . z
    dim3 gC(DSPLIT, bs);
    feat_dot<<<gC, 256, 0, stream>>>(feat, z, s_part, G, D);
    // finalize per batch
    finalize<<<bs, 256, 0, stream>>>(boxes, masks, s_part, y_new, b_vs, kptr,
                                     out_box, out_mask, out_max, G, AN, CH, CM, H);
}

// Round 2
// 92.905 us; speedup vs baseline: 1.2554x; 1.2554x over previous
//
#include <hip/hip_runtime.h>
#include <cfloat>
#include <cstdint>

#define BM 32
#define BN 64
#define BKC 32
#define APAD 34   // even -> 8B-aligned b64 rows, 2-way banks max
#define BPAD 68   // %16B==0 -> aligned b128 rows, 2-way banks max
#define DSPLIT 8

// C[M,N] = A[M,K] @ B (+bias). BT=0: B[K,N]. BT=1: B[N,K] (C = A @ B^T).
// 256 threads; each computes 2x4 outputs. A stored transposed in LDS.
__global__ __launch_bounds__(256) void gemm_tile(
    const float* __restrict__ A, const float* __restrict__ B,
    const float* __restrict__ bias, float* __restrict__ Cm,
    int M, int N, int K, int BT)
{
    __shared__ float Asm[BKC * APAD];   // Asm[kk][m]
    __shared__ float Bsm[BKC * BPAD];   // Bsm[kk][n]
    int t  = threadIdx.x;
    int m0 = blockIdx.y * BM, n0 = blockIdx.x * BN;
    int r2 = (t >> 4) * 2;      // 0..30 step 2
    int c4 = (t & 15) * 4;      // 0..60 step 4
    float acc[2][4] = {{0.f}};

    for (int k0 = 0; k0 < K; k0 += BKC) {
        // ---- stage A tile [BM x BKC], transposed into Asm[kk][m]
        {
            int m  = t >> 3;            // 0..31
            int k4 = (t & 7) * 4;       // 0..28
            float4 v = *(const float4*)&A[(size_t)(m0 + m) * K + (k0 + k4)];
            Asm[(k4 + 0) * APAD + m] = v.x;
            Asm[(k4 + 1) * APAD + m] = v.y;
            Asm[(k4 + 2) * APAD + m] = v.z;
            Asm[(k4 + 3) * APAD + m] = v.w;
        }
        // ---- stage B tile into Bsm[kk][n]
        if (!BT) {
            #pragma unroll
            for (int i = 0; i < 2; i++) {
                int r = (t >> 4) + 16 * i;      // 0..31
                float4 v = *(const float4*)&B[(size_t)(k0 + r) * N + (n0 + c4)];
                *(float4*)&Bsm[r * BPAD + c4] = v;
            }
        } else {
            #pragma unroll
            for (int i = 0; i < 2; i++) {
                int n  = (t >> 3) + 32 * i;     // 0..63
                int k4 = (t & 7) * 4;
                float4 v = *(const float4*)&B[(size_t)(n0 + n) * K + (k0 + k4)];
                Bsm[(k4 + 0) * BPAD + n] = v.x;
                Bsm[(k4 + 1) * BPAD + n] = v.y;
                Bsm[(k4 + 2) * BPAD + n] = v.z;
                Bsm[(k4 + 3) * BPAD + n] = v.w;
            }
        }
        __syncthreads();
        #pragma unroll
        for (int kk = 0; kk < BKC; kk++) {
            float2 a = *(const float2*)&Asm[kk * APAD + r2];
            float4 b = *(const float4*)&Bsm[kk * BPAD + c4];
            acc[0][0] += a.x * b.x;  acc[0][1] += a.x * b.y;
            acc[0][2] += a.x * b.z;  acc[0][3] += a.x * b.w;
            acc[1][0] += a.y * b.x;  acc[1][1] += a.y * b.y;
            acc[1][2] += a.y * b.z;  acc[1][3] += a.y * b.w;
        }
        __syncthreads();
    }
    #pragma unroll
    for (int i = 0; i < 2; i++) {
        #pragma unroll
        for (int j = 0; j < 4; j++) {
            float v = acc[i][j];
            if (bias) v += bias[n0 + c4 + j];
            Cm[(size_t)(m0 + r2 + i) * N + (n0 + c4 + j)] = v;
        }
    }
}

// s_part[b,g,ds] = sum_{d in chunk ds} feat[b,d,g] * z[b,d]
__global__ __launch_bounds__(256) void feat_dot(
    const float* __restrict__ feat, const float* __restrict__ z,
    float* __restrict__ s_part, int G, int D)
{
    int b = blockIdx.y, ds = blockIdx.x;
    int dchunk = D / DSPLIT;                       // 128
    __shared__ float zs[256];
    int t = threadIdx.x;
    if (t < dchunk) zs[t] = z[(size_t)b * D + (size_t)ds * dchunk + t];
    __syncthreads();
    if (t < G) {
        const float* fp = feat + ((size_t)b * D + (size_t)ds * dchunk) * G + t;
        float acc = 0.f;
        #pragma unroll 16
        for (int d = 0; d < dchunk; d++) acc += fp[(size_t)d * G] * zs[d];
        s_part[((size_t)b * G + t) * DSPLIT + ds] = acc;
    }
}

// per-batch finalize
__global__ __launch_bounds__(256) void finalize(
    const float* __restrict__ boxes, const float* __restrict__ masks,
    const float* __restrict__ s_part, const float* __restrict__ y_new,
    const float* __restrict__ b_vs, const int* __restrict__ kptr,
    float* __restrict__ out_box, float* __restrict__ out_mask,
    float* __restrict__ out_max,
    int G, int AN, int CH, int CM, int H)
{
    __shared__ float ms[176];
    __shared__ int   selg[176];
    __shared__ float simv[176];
    __shared__ float redw[4];
    __shared__ float bb_s;
    __shared__ int   sel_pair[2];

    int b = blockIdx.x, t = threadIdx.x;
    int k = *kptr; if (k > G) k = G;

    if (t < G) {
        const float* bp = boxes + (size_t)(b * G + t) * AN * CH;
        float s = 0.f;
        for (int a = 0; a < AN; a++) s += bp[a * CH + 4];
        ms[t] = s / (float)AN;
    }
    float part = 0.f;
    for (int h = t; h < H; h += 256) part += b_vs[h] * y_new[(size_t)b * H + h];
    #pragma unroll
    for (int off = 32; off > 0; off >>= 1) part += __shfl_down(part, off);
    if ((t & 63) == 0) redw[t >> 6] = part;
    __syncthreads();
    if (t == 0) bb_s = redw[0] + redw[1] + redw[2] + redw[3];

    // exact top-k via rank (value desc, index asc) -- matches lax.top_k ties
    if (t < G) {
        float mv = ms[t];
        int rank = 0;
        for (int g = 0; g < G; g++) {
            float o = ms[g];
            rank += (int)((o > mv) | ((o == mv) & (g < t)));
        }
        if (rank < k) selg[rank] = t;
    }
    __syncthreads();

    if (t < k) {
        const float* sp = s_part + ((size_t)b * G + selg[t]) * DSPLIT;
        float s = 0.f;
        #pragma unroll
        for (int i = 0; i < DSPLIT; i++) s += sp[i];
        simv[t] = s;
    }
    __syncthreads();

    if (t == 0) {
        float best = -FLT_MAX; int br = 0;
        for (int r = 0; r < k; r++) if (simv[r] > best) { best = simv[r]; br = r; }
        int gs = selg[br];
        const float* bp = boxes + (size_t)(b * G + gs) * AN * CH;
        float bo = -FLT_MAX; int ai = 0;
        for (int a = 0; a < AN; a++) { float o = bp[a * CH + 4]; if (o > bo) { bo = o; ai = a; } }
        float cx = bp[ai * CH + 0], cy = bp[ai * CH + 1];
        float w  = bp[ai * CH + 2], hh = bp[ai * CH + 3];
        float x1 = cx - w * 0.5f, y1 = cy - hh * 0.5f;
        out_box[(size_t)b * CH + 0] = x1;
        out_box[(size_t)b * CH + 1] = y1;
        out_box[(size_t)b * CH + 2] = x1 + w;
        out_box[(size_t)b * CH + 3] = y1 + hh;
        for (int c = 4; c < CH; c++) out_box[(size_t)b * CH + c] = bp[ai * CH + c];
        out_max[b] = best + bb_s;
        sel_pair[0] = gs; sel_pair[1] = ai;
    }
    __syncthreads();
    if (t < CM) {
        out_mask[(size_t)b * CM + t] =
            masks[((size_t)(b * G + sel_pair[0]) * AN + sel_pair[1]) * CM + t];
    }
}

extern "C" void kernel_launch(void* const* d_in, const int* in_sizes, int n_in,
                              void* d_out, int out_size, void* d_ws, size_t ws_size,
                              hipStream_t stream)
{
    const float* boxes = (const float*)d_in[0];
    const float* masks = (const float*)d_in[1];
    const float* feat  = (const float*)d_in[2];
    const float* lang  = (const float*)d_in[3];
    const float* W_vs  = (const float*)d_in[4];
    const float* b_vs  = (const float*)d_in[5];
    const float* W_ts  = (const float*)d_in[6];
    const float* b_ts  = (const float*)d_in[7];
    const int*   kptr  = (const int*)d_in[8];

    int H  = in_sizes[5];                 // 512
    int D  = in_sizes[4] / H;             // 1024
    int bs = in_sizes[3] / H;             // 256
    int G  = in_sizes[2] / (bs * D);      // 169
    int AN = 3;
    int CH = in_sizes[0] / (bs * G * AN); // 5
    int CM = in_sizes[1] / (bs * G * AN); // 32

    float* y_new  = (float*)d_ws;                    // bs*H
    float* z      = y_new + (size_t)bs * H;          // bs*D
    float* s_part = z + (size_t)bs * D;              // bs*G*DSPLIT

    float* out_box  = (float*)d_out;
    float* out_mask = out_box + (size_t)bs * CH;
    float* out_max  = out_mask + (size_t)bs * CM;

    // y_new[bs,H] = lang[bs,H] @ W_ts[H,H] + b_ts
    dim3 gA(H / BN, bs / BM);
    gemm_tile<<<gA, 256, 0, stream>>>(lang, W_ts, b_ts, y_new, bs, H, H, 0);
    // z[bs,D] = y_new[bs,H] @ W_vs[D,H]^T
    dim3 gB(D / BN, bs / BM);
    gemm_tile<<<gB, 256, 0, stream>>>(y_new, W_vs, nullptr, z, bs, D, H, 1);
    // s_part = partial feat . z
    dim3 gC(DSPLIT, bs);
    feat_dot<<<gC, 256, 0, stream>>>(feat, z, s_part, G, D);
    // finalize per batch
    finalize<<<bs, 256, 0, stream>>>(boxes, masks, s_part, y_new, b_vs, kptr,
                                     out_box, out_mask, out_max, G, AN, CH, CM, H);
}

// Round 3
// 85.050 us; speedup vs baseline: 1.3713x; 1.0924x over previous
//
#include <hip/hip_runtime.h>
#include <cfloat>
#include <cstdint>

#define BM 32
#define BN 64
#define BKC 32
#define APAD 34   // even -> 8B-aligned rows for A frags, <=2-way banks
#define BPAD 68   // 16B-aligned rows for B float4 frags, <=2-way banks
#define DSPLIT 8
#define ROWG 16   // feat rows staged per group

// C[M,N] = A[M,K] @ B (+bias). BT=0: B[K,N]. BT=1: B[N,K] (C = A @ B^T).
// 256 threads, 2x4 outputs/thread, global->reg prefetch of tile k+1 (T14).
__global__ __launch_bounds__(256) void gemm_tile(
    const float* __restrict__ A, const float* __restrict__ B,
    const float* __restrict__ bias, float* __restrict__ Cm,
    int M, int N, int K, int BT)
{
    __shared__ float Asm[BKC * APAD];   // Asm[kk][m]
    __shared__ float Bsm[BKC * BPAD];   // Bsm[kk][n]
    int t  = threadIdx.x;
    int m0 = blockIdx.y * BM, n0 = blockIdx.x * BN;
    int r2 = (t >> 4) * 2;
    int c4 = (t & 15) * 4;
    int am = t >> 3, ak4 = (t & 7) * 4;   // A-stage coords (32 x 32 tile)
    int br = t >> 4;                       // B-stage row (BT=0)
    int bn = t >> 3;                       // B-stage n (BT=1)
    float acc[2][4] = {{0.f}};

    float4 ra, rb0, rb1;
    // prologue: load tile 0 into regs
    ra = *(const float4*)&A[(size_t)(m0 + am) * K + ak4];
    if (!BT) {
        rb0 = *(const float4*)&B[(size_t)(br)      * N + (n0 + c4)];
        rb1 = *(const float4*)&B[(size_t)(br + 16) * N + (n0 + c4)];
    } else {
        rb0 = *(const float4*)&B[(size_t)(n0 + bn)      * K + ak4];
        rb1 = *(const float4*)&B[(size_t)(n0 + bn + 32) * K + ak4];
    }

    for (int k0 = 0; k0 < K; k0 += BKC) {
        // regs -> LDS
        Asm[(ak4 + 0) * APAD + am] = ra.x;
        Asm[(ak4 + 1) * APAD + am] = ra.y;
        Asm[(ak4 + 2) * APAD + am] = ra.z;
        Asm[(ak4 + 3) * APAD + am] = ra.w;
        if (!BT) {
            *(float4*)&Bsm[(br)      * BPAD + c4] = rb0;
            *(float4*)&Bsm[(br + 16) * BPAD + c4] = rb1;
        } else {
            Bsm[(ak4 + 0) * BPAD + bn] = rb0.x;
            Bsm[(ak4 + 1) * BPAD + bn] = rb0.y;
            Bsm[(ak4 + 2) * BPAD + bn] = rb0.z;
            Bsm[(ak4 + 3) * BPAD + bn] = rb0.w;
            Bsm[(ak4 + 0) * BPAD + bn + 32] = rb1.x;
            Bsm[(ak4 + 1) * BPAD + bn + 32] = rb1.y;
            Bsm[(ak4 + 2) * BPAD + bn + 32] = rb1.z;
            Bsm[(ak4 + 3) * BPAD + bn + 32] = rb1.w;
        }
        __syncthreads();
        // issue next-tile loads early; waitcnt lands at next iter's LDS write
        int kn = k0 + BKC;
        if (kn < K) {
            ra = *(const float4*)&A[(size_t)(m0 + am) * K + (kn + ak4)];
            if (!BT) {
                rb0 = *(const float4*)&B[(size_t)(kn + br)      * N + (n0 + c4)];
                rb1 = *(const float4*)&B[(size_t)(kn + br + 16) * N + (n0 + c4)];
            } else {
                rb0 = *(const float4*)&B[(size_t)(n0 + bn)      * K + (kn + ak4)];
                rb1 = *(const float4*)&B[(size_t)(n0 + bn + 32) * K + (kn + ak4)];
            }
        }
        #pragma unroll
        for (int kk = 0; kk < BKC; kk++) {
            float2 a = *(const float2*)&Asm[kk * APAD + r2];
            float4 b = *(const float4*)&Bsm[kk * BPAD + c4];
            acc[0][0] += a.x * b.x;  acc[0][1] += a.x * b.y;
            acc[0][2] += a.x * b.z;  acc[0][3] += a.x * b.w;
            acc[1][0] += a.y * b.x;  acc[1][1] += a.y * b.y;
            acc[1][2] += a.y * b.z;  acc[1][3] += a.y * b.w;
        }
        __syncthreads();
    }
    #pragma unroll
    for (int i = 0; i < 2; i++)
        #pragma unroll
        for (int j = 0; j < 4; j++) {
            float v = acc[i][j];
            if (bias) v += bias[n0 + c4 + j];
            Cm[(size_t)(m0 + r2 + i) * N + (n0 + c4 + j)] = v;
        }
}

// s_part[b,g,ds] = sum_{d in chunk ds} feat[b,d,g] * z[b,d]
// float4 LDS staging of 16-row groups, reg-prefetch of next group.
__global__ __launch_bounds__(256) void feat_dot(
    const float* __restrict__ feat, const float* __restrict__ z,
    float* __restrict__ s_part, int G, int D)
{
    const int b = blockIdx.y, ds = blockIdx.x;
    const int dchunk = D / DSPLIT;              // 128
    const int ngrp = dchunk / ROWG;             // 8
    const int grpVec = (ROWG * G) / 4;          // 676 float4 (16B-aligned groups)
    __shared__ float buf[ROWG * 169];           // 2704 floats, flat [r*G + g]
    __shared__ float zs[128];
    int t = threadIdx.x;

    if (t < dchunk) zs[t] = z[(size_t)b * D + (size_t)ds * dchunk + t];

    const size_t slab = ((size_t)b * D + (size_t)ds * dchunk) * G;
    float4 r0, r1, r2;
    {   // prologue: group 0
        const float4* p = (const float4*)(feat + slab);
        r0 = p[t]; r1 = p[t + 256];
        if (t + 512 < grpVec) r2 = p[t + 512];
    }
    float acc = 0.f;
    for (int gi = 0; gi < ngrp; gi++) {
        *(float4*)&buf[4 * t] = r0;
        *(float4*)&buf[4 * (t + 256)] = r1;
        if (t + 512 < grpVec) *(float4*)&buf[4 * (t + 512)] = r2;
        __syncthreads();
        if (gi + 1 < ngrp) {
            const float4* p = (const float4*)(feat + slab + (size_t)(gi + 1) * ROWG * G);
            r0 = p[t]; r1 = p[t + 256];
            if (t + 512 < grpVec) r2 = p[t + 512];
        }
        if (t < G) {
            #pragma unroll
            for (int r = 0; r < ROWG; r++)
                acc += buf[r * G + t] * zs[gi * ROWG + r];
        }
        __syncthreads();
    }
    if (t < G) s_part[((size_t)b * G + t) * DSPLIT + ds] = acc;
}

// per-batch finalize
__global__ __launch_bounds__(256) void finalize(
    const float* __restrict__ boxes, const float* __restrict__ masks,
    const float* __restrict__ s_part, const float* __restrict__ y_new,
    const float* __restrict__ b_vs, const int* __restrict__ kptr,
    float* __restrict__ out_box, float* __restrict__ out_mask,
    float* __restrict__ out_max,
    int G, int AN, int CH, int CM, int H)
{
    __shared__ float ms[176];
    __shared__ int   selg[176];
    __shared__ float simv[176];
    __shared__ float redw[4];
    __shared__ float bb_s;
    __shared__ int   sel_pair[2];

    int b = blockIdx.x, t = threadIdx.x;
    int k = *kptr; if (k > G) k = G;

    if (t < G) {
        const float* bp = boxes + (size_t)(b * G + t) * AN * CH;
        float s = 0.f;
        for (int a = 0; a < AN; a++) s += bp[a * CH + 4];
        ms[t] = s / (float)AN;
    }
    float part = 0.f;
    for (int h = t; h < H; h += 256) part += b_vs[h] * y_new[(size_t)b * H + h];
    #pragma unroll
    for (int off = 32; off > 0; off >>= 1) part += __shfl_down(part, off);
    if ((t & 63) == 0) redw[t >> 6] = part;
    __syncthreads();
    if (t == 0) bb_s = redw[0] + redw[1] + redw[2] + redw[3];

    // exact top-k via rank (value desc, index asc) -- matches lax.top_k ties
    if (t < G) {
        float mv = ms[t];
        int rank = 0;
        for (int g = 0; g < G; g++) {
            float o = ms[g];
            rank += (int)((o > mv) | ((o == mv) & (g < t)));
        }
        if (rank < k) selg[rank] = t;
    }
    __syncthreads();

    if (t < k) {
        const float* sp = s_part + ((size_t)b * G + selg[t]) * DSPLIT;
        float s = 0.f;
        #pragma unroll
        for (int i = 0; i < DSPLIT; i++) s += sp[i];
        simv[t] = s;
    }
    __syncthreads();

    if (t == 0) {
        float best = -FLT_MAX; int br = 0;
        for (int r = 0; r < k; r++) if (simv[r] > best) { best = simv[r]; br = r; }
        int gs = selg[br];
        const float* bp = boxes + (size_t)(b * G + gs) * AN * CH;
        float bo = -FLT_MAX; int ai = 0;
        for (int a = 0; a < AN; a++) { float o = bp[a * CH + 4]; if (o > bo) { bo = o; ai = a; } }
        float cx = bp[ai * CH + 0], cy = bp[ai * CH + 1];
        float w  = bp[ai * CH + 2], hh = bp[ai * CH + 3];
        float x1 = cx - w * 0.5f, y1 = cy - hh * 0.5f;
        out_box[(size_t)b * CH + 0] = x1;
        out_box[(size_t)b * CH + 1] = y1;
        out_box[(size_t)b * CH + 2] = x1 + w;
        out_box[(size_t)b * CH + 3] = y1 + hh;
        for (int c = 4; c < CH; c++) out_box[(size_t)b * CH + c] = bp[ai * CH + c];
        out_max[b] = best + bb_s;
        sel_pair[0] = gs; sel_pair[1] = ai;
    }
    __syncthreads();
    if (t < CM) {
        out_mask[(size_t)b * CM + t] =
            masks[((size_t)(b * G + sel_pair[0]) * AN + sel_pair[1]) * CM + t];
    }
}

extern "C" void kernel_launch(void* const* d_in, const int* in_sizes, int n_in,
                              void* d_out, int out_size, void* d_ws, size_t ws_size,
                              hipStream_t stream)
{
    const float* boxes = (const float*)d_in[0];
    const float* masks = (const float*)d_in[1];
    const float* feat  = (const float*)d_in[2];
    const float* lang  = (const float*)d_in[3];
    const float* W_vs  = (const float*)d_in[4];
    const float* b_vs  = (const float*)d_in[5];
    const float* W_ts  = (const float*)d_in[6];
    const float* b_ts  = (const float*)d_in[7];
    const int*   kptr  = (const int*)d_in[8];

    int H  = in_sizes[5];                 // 512
    int D  = in_sizes[4] / H;             // 1024
    int bs = in_sizes[3] / H;             // 256
    int G  = in_sizes[2] / (bs * D);      // 169
    int AN = 3;
    int CH = in_sizes[0] / (bs * G * AN); // 5
    int CM = in_sizes[1] / (bs * G * AN); // 32

    float* y_new  = (float*)d_ws;                    // bs*H
    float* z      = y_new + (size_t)bs * H;          // bs*D
    float* s_part = z + (size_t)bs * D;              // bs*G*DSPLIT

    float* out_box  = (float*)d_out;
    float* out_mask = out_box + (size_t)bs * CH;
    float* out_max  = out_mask + (size_t)bs * CM;

    dim3 gA(H / BN, bs / BM);
    gemm_tile<<<gA, 256, 0, stream>>>(lang, W_ts, b_ts, y_new, bs, H, H, 0);
    dim3 gB(D / BN, bs / BM);
    gemm_tile<<<gB, 256, 0, stream>>>(y_new, W_vs, nullptr, z, bs, D, H, 1);
    dim3 gC(DSPLIT, bs);
    feat_dot<<<gC, 256, 0, stream>>>(feat, z, s_part, G, D);
    finalize<<<bs, 256, 0, stream>>>(boxes, masks, s_part, y_new, b_vs, kptr,
                                     out_box, out_mask, out_max, G, AN, CH, CM, H);
}

// Round 4
// 61.550 us; speedup vs baseline: 1.8949x; 1.3818x over previous
//
#include <hip/hip_runtime.h>
#include <cfloat>
#include <cstdint>

#define GBM 64
#define GBN 64
#define GBK 64
#define GPAD 68     // 68*4=272B rows: 16B-aligned for b128 frags
#define DSPLIT 8
#define ROWG 16

typedef unsigned int u32;

__device__ __forceinline__ void gload_lds16(const float* g, float* l) {
    __builtin_amdgcn_global_load_lds(
        (const __attribute__((address_space(1))) u32*)g,
        (__attribute__((address_space(3))) u32*)l, 16, 0, 0);
}

// ---- split-K GEMM: Cpart[z][M][N] for one 64x64x64 tile per block ----------
// BT=0: B[K][N].  BT=1: B[N][K] (C = A @ B^T). 256 thr, 4x4 microtile.
__global__ __launch_bounds__(256) void gemm_splitk(
    const float* __restrict__ A, const float* __restrict__ B,
    float* __restrict__ Cpart, int M, int N, int K, int BT)
{
    __shared__ __align__(16) float Asm[GBK][GPAD];  // [kk][m]
    __shared__ __align__(16) float Bsm[GBK][GPAD];  // [kk][n]
    int t  = threadIdx.x;
    int m0 = blockIdx.y * GBM, n0 = blockIdx.x * GBN;
    int ks = blockIdx.z * GBK;

    #pragma unroll
    for (int i = 0; i < 4; i++) {                   // A: 64x64 = 1024 float4
        int v = t + 256 * i;
        int m = v >> 4, k4 = (v & 15) * 4;
        float4 x = *(const float4*)&A[(size_t)(m0 + m) * K + ks + k4];
        Asm[k4 + 0][m] = x.x; Asm[k4 + 1][m] = x.y;
        Asm[k4 + 2][m] = x.z; Asm[k4 + 3][m] = x.w;
    }
    if (!BT) {
        #pragma unroll
        for (int i = 0; i < 4; i++) {
            int v = t + 256 * i;
            int r = v >> 4, c4 = (v & 15) * 4;
            *(float4*)&Bsm[r][c4] = *(const float4*)&B[(size_t)(ks + r) * N + n0 + c4];
        }
    } else {
        #pragma unroll
        for (int i = 0; i < 4; i++) {
            int v = t + 256 * i;
            int n = v >> 4, k4 = (v & 15) * 4;
            float4 x = *(const float4*)&B[(size_t)(n0 + n) * K + ks + k4];
            Bsm[k4 + 0][n] = x.x; Bsm[k4 + 1][n] = x.y;
            Bsm[k4 + 2][n] = x.z; Bsm[k4 + 3][n] = x.w;
        }
    }
    __syncthreads();

    int r4 = (t >> 4) * 4, c4 = (t & 15) * 4;
    float acc[4][4] = {{0.f}};
    #pragma unroll
    for (int kk = 0; kk < GBK; kk++) {
        float4 a = *(const float4*)&Asm[kk][r4];    // broadcast within 16-group
        float4 b = *(const float4*)&Bsm[kk][c4];
        float av[4] = {a.x, a.y, a.z, a.w};
        float bv[4] = {b.x, b.y, b.z, b.w};
        #pragma unroll
        for (int i = 0; i < 4; i++)
            #pragma unroll
            for (int j = 0; j < 4; j++) acc[i][j] += av[i] * bv[j];
    }
    float* Cp = Cpart + (size_t)blockIdx.z * M * N;
    #pragma unroll
    for (int i = 0; i < 4; i++) {
        float4 v = {acc[i][0], acc[i][1], acc[i][2], acc[i][3]};
        *(float4*)&Cp[(size_t)(m0 + r4 + i) * N + n0 + c4] = v;
    }
}

// ---- out[i] = sum_s in[s*len+i] (+bias[i % N], N pow2) ---------------------
__global__ __launch_bounds__(256) void reduce_bias(
    const float* __restrict__ in, const float* __restrict__ bias,
    float* __restrict__ out, int len, int Nmask, int S)
{
    int i = (blockIdx.x * 256 + threadIdx.x) * 4;
    if (i >= len) return;
    float4 a = *(const float4*)&in[i];
    for (int s = 1; s < S; s++) {
        float4 b = *(const float4*)&in[(size_t)s * len + i];
        a.x += b.x; a.y += b.y; a.z += b.z; a.w += b.w;
    }
    if (bias) {
        float4 b = *(const float4*)&bias[i & Nmask];
        a.x += b.x; a.y += b.y; a.z += b.z; a.w += b.w;
    }
    *(float4*)&out[i] = a;
}

// ---- s_part[b,g,ds] = sum_{d in chunk ds} feat[b,d,g] * z[b,d] -------------
// z summed from split-K partials on load; feat staged via global_load_lds DMA,
// double-buffered, one barrier per 16-row group.
__global__ __launch_bounds__(256) void feat_dot(
    const float* __restrict__ feat, const float* __restrict__ zpart,
    float* __restrict__ s_part, int G, int D, int bs)
{
    const int b = blockIdx.y, ds = blockIdx.x;
    const int dchunk = D / DSPLIT;          // 128
    const int ngrp = dchunk / ROWG;         // 8
    const int grpVec = ROWG * G / 4;        // 676 float4 per group
    __shared__ float4 bufv[2][676];
    __shared__ __align__(16) float zs[128];
    int t  = threadIdx.x;
    int wb = t & ~63;                       // wave-uniform base

    if (t < dchunk) {
        float s = 0.f;
        #pragma unroll
        for (int sp = 0; sp < DSPLIT; sp++)
            s += zpart[((size_t)sp * bs + b) * D + ds * dchunk + t];
        zs[t] = s;
    }

    const float* gsrc = feat + ((size_t)b * D + (size_t)ds * dchunk) * G;
    {   // prologue: DMA group 0 into buffer 0
        float* dst = (float*)bufv[0];
        gload_lds16(gsrc + 4 * t,         dst + 4 * wb);
        gload_lds16(gsrc + 4 * (t + 256), dst + 4 * (wb + 256));
        if (t + 512 < grpVec)
            gload_lds16(gsrc + 4 * (t + 512), dst + 4 * (wb + 512));
    }
    __syncthreads();

    float acc = 0.f;
    int cur = 0;
    for (int gi = 0; gi < ngrp; gi++) {
        if (gi + 1 < ngrp) {                // issue next-group DMA first
            const float* gs = gsrc + (size_t)(gi + 1) * (grpVec * 4);
            float* dst = (float*)bufv[cur ^ 1];
            gload_lds16(gs + 4 * t,         dst + 4 * wb);
            gload_lds16(gs + 4 * (t + 256), dst + 4 * (wb + 256));
            if (t + 512 < grpVec)
                gload_lds16(gs + 4 * (t + 512), dst + 4 * (wb + 512));
        }
        if (t < G) {
            const float* bp = (const float*)bufv[cur];
            #pragma unroll
            for (int r4 = 0; r4 < ROWG / 4; r4++) {
                float4 zv = *(const float4*)&zs[gi * ROWG + r4 * 4];
                acc += bp[(r4 * 4 + 0) * G + t] * zv.x;
                acc += bp[(r4 * 4 + 1) * G + t] * zv.y;
                acc += bp[(r4 * 4 + 2) * G + t] * zv.z;
                acc += bp[(r4 * 4 + 3) * G + t] * zv.w;
            }
        }
        __syncthreads();                    // drains DMA for next buffer too
        cur ^= 1;
    }
    if (t < G) s_part[((size_t)b * G + t) * DSPLIT + ds] = acc;
}

// ---- per-batch finalize ----------------------------------------------------
__global__ __launch_bounds__(256) void finalize(
    const float* __restrict__ boxes, const float* __restrict__ masks,
    const float* __restrict__ s_part, const float* __restrict__ y_new,
    const float* __restrict__ b_vs, const int* __restrict__ kptr,
    float* __restrict__ out_box, float* __restrict__ out_mask,
    float* __restrict__ out_max,
    int G, int AN, int CH, int CM, int H)
{
    __shared__ float ms[176];
    __shared__ int   selg[176];
    __shared__ float simv[176];
    __shared__ float redw[4];
    __shared__ float bb_s;
    __shared__ int   sel_pair[2];

    int b = blockIdx.x, t = threadIdx.x;
    int k = *kptr; if (k > G) k = G;

    if (t < G) {
        const float* bp = boxes + (size_t)(b * G + t) * AN * CH;
        float s = 0.f;
        for (int a = 0; a < AN; a++) s += bp[a * CH + 4];
        ms[t] = s / (float)AN;
    }
    float part = 0.f;
    for (int h = t; h < H; h += 256) part += b_vs[h] * y_new[(size_t)b * H + h];
    #pragma unroll
    for (int off = 32; off > 0; off >>= 1) part += __shfl_down(part, off);
    if ((t & 63) == 0) redw[t >> 6] = part;
    __syncthreads();
    if (t == 0) bb_s = redw[0] + redw[1] + redw[2] + redw[3];

    // exact top-k via rank (value desc, index asc) -- matches lax.top_k ties
    if (t < G) {
        float mv = ms[t];
        int rank = 0;
        for (int g = 0; g < G; g++) {
            float o = ms[g];
            rank += (int)((o > mv) | ((o == mv) & (g < t)));
        }
        if (rank < k) selg[rank] = t;
    }
    __syncthreads();

    if (t < k) {
        const float* sp = s_part + ((size_t)b * G + selg[t]) * DSPLIT;
        float s = 0.f;
        #pragma unroll
        for (int i = 0; i < DSPLIT; i++) s += sp[i];
        simv[t] = s;
    }
    __syncthreads();

    if (t == 0) {
        float best = -FLT_MAX; int br = 0;
        for (int r = 0; r < k; r++) if (simv[r] > best) { best = simv[r]; br = r; }
        int gs = selg[br];
        const float* bp = boxes + (size_t)(b * G + gs) * AN * CH;
        float bo = -FLT_MAX; int ai = 0;
        for (int a = 0; a < AN; a++) { float o = bp[a * CH + 4]; if (o > bo) { bo = o; ai = a; } }
        float cx = bp[ai * CH + 0], cy = bp[ai * CH + 1];
        float w  = bp[ai * CH + 2], hh = bp[ai * CH + 3];
        float x1 = cx - w * 0.5f, y1 = cy - hh * 0.5f;
        out_box[(size_t)b * CH + 0] = x1;
        out_box[(size_t)b * CH + 1] = y1;
        out_box[(size_t)b * CH + 2] = x1 + w;
        out_box[(size_t)b * CH + 3] = y1 + hh;
        for (int c = 4; c < CH; c++) out_box[(size_t)b * CH + c] = bp[ai * CH + c];
        out_max[b] = best + bb_s;
        sel_pair[0] = gs; sel_pair[1] = ai;
    }
    __syncthreads();
    if (t < CM) {
        out_mask[(size_t)b * CM + t] =
            masks[((size_t)(b * G + sel_pair[0]) * AN + sel_pair[1]) * CM + t];
    }
}

extern "C" void kernel_launch(void* const* d_in, const int* in_sizes, int n_in,
                              void* d_out, int out_size, void* d_ws, size_t ws_size,
                              hipStream_t stream)
{
    const float* boxes = (const float*)d_in[0];
    const float* masks = (const float*)d_in[1];
    const float* feat  = (const float*)d_in[2];
    const float* lang  = (const float*)d_in[3];
    const float* W_vs  = (const float*)d_in[4];
    const float* b_vs  = (const float*)d_in[5];
    const float* W_ts  = (const float*)d_in[6];
    const float* b_ts  = (const float*)d_in[7];
    const int*   kptr  = (const int*)d_in[8];

    int H  = in_sizes[5];                 // 512
    int D  = in_sizes[4] / H;             // 1024
    int bs = in_sizes[3] / H;             // 256
    int G  = in_sizes[2] / (bs * D);      // 169
    int AN = 3;
    int CH = in_sizes[0] / (bs * G * AN); // 5
    int CM = in_sizes[1] / (bs * G * AN); // 32
    const int S = 8;                      // split-K slices (K = 512 = S*64)

    float* py     = (float*)d_ws;                       // S*bs*H
    float* y_new  = py + (size_t)S * bs * H;            // bs*H
    float* pz     = y_new + (size_t)bs * H;             // S*bs*D
    float* s_part = pz + (size_t)S * bs * D;            // bs*G*DSPLIT

    float* out_box  = (float*)d_out;
    float* out_mask = out_box + (size_t)bs * CH;
    float* out_max  = out_mask + (size_t)bs * CM;

    // partial y = lang @ W_ts  (split-K)
    dim3 g1(H / GBN, bs / GBM, S);
    gemm_splitk<<<g1, 256, 0, stream>>>(lang, W_ts, py, bs, H, H, 0);
    // y_new = sum_s py + b_ts
    int len1 = bs * H;
    reduce_bias<<<len1 / 4 / 256, 256, 0, stream>>>(py, b_ts, y_new, len1, H - 1, S);
    // partial z = y_new @ W_vs^T  (split-K; reduction folded into feat_dot)
    dim3 g2(D / GBN, bs / GBM, S);
    gemm_splitk<<<g2, 256, 0, stream>>>(y_new, W_vs, pz, bs, D, H, 1);
    // s_part = partial feat . z
    dim3 gC(DSPLIT, bs);
    feat_dot<<<gC, 256, 0, stream>>>(feat, pz, s_part, G, D, bs);
    // finalize per batch
    finalize<<<bs, 256, 0, stream>>>(boxes, masks, s_part, y_new, b_vs, kptr,
                                     out_box, out_mask, out_max, G, AN, CH, CM, H);
}